// Round 6
// baseline (319.950 us; speedup 1.0000x reference)
//
#include <hip/hip_runtime.h>

typedef unsigned short u16;
typedef unsigned int   u32;
typedef __bf16 bf16x8 __attribute__((ext_vector_type(8)));
typedef float  f32x4  __attribute__((ext_vector_type(4)));

__device__ __forceinline__ u16 f2b(float f) {
  u32 u = __builtin_bit_cast(u32, f);
  u = (u + 0x7fffu + ((u >> 16) & 1u)) >> 16;   // RNE
  return (u16)u;
}
__device__ __forceinline__ float b2f(u16 h) {
  u32 u = ((u32)h) << 16;
  return __builtin_bit_cast(float, u);
}
__device__ __forceinline__ float ld_in(const void* p, size_t idx, int isf32) {
  return isf32 ? ((const float*)p)[idx] : b2f(((const u16*)p)[idx]);
}
// async 16B global->LDS; HW semantics: LDS dest = wave-uniform base + lane*16
__device__ __forceinline__ void async_cp16(const u16* g, u16* l) {
  __builtin_amdgcn_global_load_lds(
      (const __attribute__((address_space(1))) void*)g,
      (__attribute__((address_space(3))) void*)l, 16, 0, 0);
}

// Constants: BS=1024, CH=3, IMG=64, K=16, NC=10, HID=1024, LAT=128
// OH=4, L=16, PD=768, M=16384. ws observed 256MB -> single pass R=16384.
#define RECON_ELEMS 12582912   // 1024*3*64*64

// ---------------------------------------------------------------------------
// dtype detector: bf16 uniform[0,1) values are u16 in [0,0x3F80], sign=0.
// ---------------------------------------------------------------------------
__global__ __launch_bounds__(256) void detect_f32(const u16* __restrict__ x,
                                                  int* __restrict__ flag) {
  __shared__ int s;
  if (threadIdx.x == 0) s = 0;
  __syncthreads();
  int bad = 0;
  for (int i = threadIdx.x; i < 2048; i += 256) {
    u16 u = x[i];
    if ((u & 0x8000u) || (u > 0x3F80u)) bad = 1;
  }
  if (bad) atomicOr(&s, 1);
  __syncthreads();
  if (threadIdx.x == 0) *flag = s;
}

// ---------------------------------------------------------------------------
// A1 chunk (R x 800 bf16): [patch(768) | c(10) | zeros(22)]
// ---------------------------------------------------------------------------
__global__ __launch_bounds__(256) void build_a1(const void* __restrict__ x,
                                                const void* __restrict__ c,
                                                u16* __restrict__ A1,
                                                int R, int rowOff,
                                                const int* __restrict__ flag) {
  int g = blockIdx.x * 256 + threadIdx.x;          // R * 100 groups of 8 cols
  if (g >= R * 100) return;
  int row = g / 100, grp = g - row * 100;
  int grow = row + rowOff;
  int b = grow >> 4, l = grow & 15, oh = l >> 2, ow = l & 3;
  int isf = *flag;
  u16* dst = &A1[(size_t)row * 800 + grp * 8];
  int col0 = grp * 8;
  if (col0 < 768) {
    int ch = col0 >> 8, kh = (col0 >> 4) & 15, kw = col0 & 15;  // kw in {0,8}
    size_t off = (size_t)b * 12288 + ch * 4096 + (oh * 16 + kh) * 64 + ow * 16 + kw;
    if (isf) {
      const float* s = (const float*)x + off;
      float4 f0 = *(const float4*)(s);
      float4 f1 = *(const float4*)(s + 4);
      dst[0] = f2b(f0.x); dst[1] = f2b(f0.y); dst[2] = f2b(f0.z); dst[3] = f2b(f0.w);
      dst[4] = f2b(f1.x); dst[5] = f2b(f1.y); dst[6] = f2b(f1.z); dst[7] = f2b(f1.w);
    } else {
      *(int4*)dst = *(const int4*)((const u16*)x + off);
    }
  } else {
#pragma unroll
    for (int t = 0; t < 8; ++t) {
      int col = col0 + t;
      dst[t] = (col < 778) ? f2b(ld_in(c, (size_t)b * 10 + (col - 768), isf)) : (u16)0;
    }
  }
}

// ---------------------------------------------------------------------------
// Fused weight prep: 4 transposes in one dispatch (blockIdx.z selects).
// dst (N x Kpad) = src(Ksrc x N)^T, zero-pad k>=Ksrc. 32x32 LDS tile.
// ---------------------------------------------------------------------------
__global__ __launch_bounds__(256) void prep_weights(const void* __restrict__ ew1,
                                                    const void* __restrict__ ew2,
                                                    const void* __restrict__ dw1,
                                                    const void* __restrict__ dw2,
                                                    u16* __restrict__ W1t,
                                                    u16* __restrict__ EW2t,
                                                    u16* __restrict__ W3t,
                                                    u16* __restrict__ DW2t,
                                                    const int* __restrict__ flag) {
  const int z = blockIdx.z;
  const void* src; u16* dst; int N, Kpad, Ksrc;
  if (z == 0)      { src = ew1; dst = W1t;  N = 1024; Kpad = 800;  Ksrc = 778;  }
  else if (z == 1) { src = ew2; dst = EW2t; N = 256;  Kpad = 1024; Ksrc = 1024; }
  else if (z == 2) { src = dw1; dst = W3t;  N = 1024; Kpad = 160;  Ksrc = 138;  }
  else             { src = dw2; dst = DW2t; N = 768;  Kpad = 1024; Ksrc = 1024; }
  const int k0 = blockIdx.x * 32, n0 = blockIdx.y * 32;
  if (k0 >= Kpad || n0 >= N) return;
  __shared__ float t[32][33];
  const int tx = threadIdx.x & 31, ty = threadIdx.x >> 5;   // 32 x 8
  const int isf = *flag;
#pragma unroll
  for (int j = 0; j < 4; ++j) {
    int k = k0 + ty + j * 8;
    t[ty + j * 8][tx] = (k < Ksrc) ? ld_in(src, (size_t)k * N + n0 + tx, isf) : 0.0f;
  }
  __syncthreads();
#pragma unroll
  for (int j = 0; j < 4; ++j) {
    int n = n0 + ty + j * 8;
    dst[(size_t)n * Kpad + k0 + tx] = f2b(t[tx][ty + j * 8]);
  }
}

// A3 chunk tail cols 128..159: [c(10) | zeros(22)]
__global__ __launch_bounds__(256) void build_a3_tail(const void* __restrict__ c,
                                                     u16* __restrict__ A3,
                                                     int R, int rowOff,
                                                     const int* __restrict__ flag) {
  int i = blockIdx.x * 256 + threadIdx.x;          // R*32
  if (i >= R * 32) return;
  int row = i >> 5, col = 128 + (i & 31);
  int b = (row + rowOff) >> 4;
  int isf = *flag;
  A3[(size_t)row * 160 + col] = (col < 138) ? f2b(ld_in(c, (size_t)b * 10 + col - 128, isf)) : (u16)0;
}

// ---------------------------------------------------------------------------
// MFMA GEMM: C(R x N) = act(A(R x K) @ Bt(N x K)^T + bias)
// 128x64 tile, BK=32, 4 waves as (wrow 2 x wcol 2); wave-tile 64x32 ->
// 4x2 16x16x32 MFMA. Small tile = more blocks/CU (6-8) so independent
// blocks de-phase the barrier stalls (round-5 lesson: 128x128 @ 4/CU was
// latency-starved at MfmaUtil 14%).
// 1D grid, by = bid % GY (GY%8==0 -> XCD = by%8): A-tile sharers colocate.
// LDS 16B XOR swizzle (round-5 verified: 0 bank conflicts).
// EPI: 0 = ReLU -> bf16 outb row-major (ld=N)
//      1 = none -> f32 outf = mu_logvar_2d scatter, bf16 out1 = A3 mu (ld=160)
//      2 = sigmoid -> f32 outf = recon scatter
// ---------------------------------------------------------------------------
template <int EPI>
__global__ __launch_bounds__(256, 6) void gemm_k(const u16* __restrict__ A,
                                                 const u16* __restrict__ Bt,
                                                 const void* __restrict__ bias,
                                                 u16* __restrict__ outb,
                                                 float* __restrict__ outf,
                                                 u16* __restrict__ out1,
                                                 int N, int K, int GY, int rowOff,
                                                 const int* __restrict__ flag) {
  __shared__ __align__(16) u16 As[128 * 32];
  __shared__ __align__(16) u16 Bs[64 * 32];
  const int bid = blockIdx.x;
  const int by = bid % GY, bx = bid / GY;
  const int rowBase = by * 128, colBase = bx * 64;
  const int tid  = threadIdx.x;
  const int lane = tid & 63;
  const int wave = tid >> 6;
  const int wrow = (wave >> 1) * 64, wcol = (wave & 1) * 32;
  const int quad = lane >> 4, l16 = lane & 15;
  const int swq = quad ^ ((l16 >> 1) & 3);          // XOR-swizzled quad slot

  // staging: LDS slot s <- global chunk (r=s>>2, q=(s&3)^((s>>3)&3))
  const int s0 = tid, s1 = 256 + tid;
  const int r0 = s0 >> 2, q0 = (s0 & 3) ^ ((s0 >> 3) & 3);
  const int r1 = s1 >> 2, q1 = (s1 & 3) ^ ((s1 >> 3) & 3);
  const u16* gA0 = &A[(size_t)(rowBase + r0) * K + q0 * 8];
  const u16* gA1 = &A[(size_t)(rowBase + r1) * K + q1 * 8];
  const u16* gB0 = &Bt[(size_t)(colBase + r0) * K + q0 * 8];   // r0 in [0,64)

  f32x4 acc[4][2] = {};

  for (int k0 = 0; k0 < K; k0 += 32) {
    __syncthreads();
    async_cp16(gA0 + k0, &As[s0 * 8]);
    async_cp16(gA1 + k0, &As[s1 * 8]);
    async_cp16(gB0 + k0, &Bs[s0 * 8]);
    __syncthreads();
    bf16x8 af[4], bfr[2];
#pragma unroll
    for (int i = 0; i < 4; ++i)
      af[i] = *(const bf16x8*)(&As[(wrow + i * 16 + l16) * 32 + swq * 8]);
#pragma unroll
    for (int j = 0; j < 2; ++j)
      bfr[j] = *(const bf16x8*)(&Bs[(wcol + j * 16 + l16) * 32 + swq * 8]);
#pragma unroll
    for (int i = 0; i < 4; ++i)
#pragma unroll
      for (int j = 0; j < 2; ++j)
        acc[i][j] = __builtin_amdgcn_mfma_f32_16x16x32_bf16(af[i], bfr[j], acc[i][j], 0, 0, 0);
  }

  const int isf = *flag;
  float bv[2];
#pragma unroll
  for (int j = 0; j < 2; ++j) bv[j] = ld_in(bias, colBase + wcol + j * 16 + l16, isf);

#pragma unroll
  for (int i = 0; i < 4; ++i) {
    int row0 = rowBase + wrow + i * 16 + quad * 4;   // chunk-local
#pragma unroll
    for (int j = 0; j < 2; ++j) {
      int col = colBase + wcol + j * 16 + l16;
#pragma unroll
      for (int r = 0; r < 4; ++r) {
        int row = row0 + r;                        // chunk-local
        int grow = row + rowOff;                   // global
        float v = acc[i][j][r] + bv[j];
        if (EPI == 0) {
          v = fmaxf(v, 0.0f);
          outb[(size_t)row * N + col] = f2b(v);
        } else if (EPI == 1) {
          int b = grow >> 4, lr = grow & 15;
          outf[(size_t)b * 4096 + col * 16 + lr] = v;            // mu_logvar_2d (f32)
          if (col < 128) out1[(size_t)row * 160 + col] = f2b(v);  // A3 mu (bf16)
        } else {
          v = 1.0f / (1.0f + __expf(-v));
          int b = grow >> 4, l = grow & 15;
          int oh = l >> 2, ow = l & 3;
          int ch = col >> 8, kh = (col >> 4) & 15, kw = col & 15;
          outf[(size_t)b * 12288 + ch * 4096 + (oh * 16 + kh) * 64 + ow * 16 + kw] = v;
        }
      }
    }
  }
}

// ---------------------------------------------------------------------------
// Workspace (u16 element offsets):
//   flag @ 0 (8 u16 incl pad) | W1t 1024x800 | EW2t 256x1024 | W3t 1024x160
//   DW2t 768x1024 | A1c Rx800 | hc Rx1024 | A3c Rx160
// bytes = 2*(2031624 + R*1984); R=16384 -> 69.1 MB (ws observed = 256 MB)
// ---------------------------------------------------------------------------

extern "C" void kernel_launch(void* const* d_in, const int* in_sizes, int n_in,
                              void* d_out, int out_size, void* d_ws, size_t ws_size,
                              hipStream_t stream) {
  const void* x   = d_in[0];
  const void* c   = d_in[1];
  const void* ew1 = d_in[2];
  const void* eb1 = d_in[3];
  const void* ew2 = d_in[4];
  const void* eb2 = d_in[5];
  const void* dw1 = d_in[6];
  const void* db1 = d_in[7];
  const void* dw2 = d_in[8];
  const void* db2 = d_in[9];
  float* out  = (float*)d_out;
  u16*   ws   = (u16*)d_ws;

  const size_t fixedU16 = 8 + 819200 + 262144 + 163840 + 786432;  // 2,031,624
  int R = 128;
  for (int cand = 16384; cand >= 128; cand >>= 1) {
    if ((fixedU16 + (size_t)cand * 1984) * 2 <= ws_size) { R = cand; break; }
  }

  int* flag = (int*)ws;
  u16* W1t  = ws + 8;
  u16* EW2t = W1t + 819200;
  u16* W3t  = EW2t + 262144;
  u16* DW2t = W3t + 163840;
  u16* A1c  = DW2t + 786432;
  u16* hc   = A1c + (size_t)R * 800;
  u16* A3c  = hc + (size_t)R * 1024;
  float* out2 = out + RECON_ELEMS;

  detect_f32<<<dim3(1), dim3(256), 0, stream>>>((const u16*)x, flag);

  prep_weights<<<dim3(32, 32, 4), dim3(256), 0, stream>>>(ew1, ew2, dw1, dw2,
                                                          W1t, EW2t, W3t, DW2t, flag);

  const int chunks = 16384 / R;
  const int GY = R / 128;
  for (int chunk = 0; chunk < chunks; ++chunk) {
    int rowOff = chunk * R;
    build_a1<<<dim3((R * 100 + 255) / 256), dim3(256), 0, stream>>>(x, c, A1c, R, rowOff, flag);
    build_a3_tail<<<dim3((R * 32) / 256), dim3(256), 0, stream>>>(c, A3c, R, rowOff, flag);
    // enc1: h = relu(A1 @ W1 + b1), N=1024 K=800
    gemm_k<0><<<dim3(16 * GY), dim3(256), 0, stream>>>(A1c, W1t, eb1, hc, nullptr, nullptr, 1024, 800, GY, rowOff, flag);
    // enc2: mu_logvar = h @ W2 + b2, N=256 K=1024 (f32 scatter + A3 mu)
    gemm_k<1><<<dim3(4 * GY), dim3(256), 0, stream>>>(hc, EW2t, eb2, nullptr, out2, A3c, 256, 1024, GY, rowOff, flag);
    // dec1: hd = relu(A3 @ W3 + b3), N=1024 K=160
    gemm_k<0><<<dim3(16 * GY), dim3(256), 0, stream>>>(A3c, W3t, db1, hc, nullptr, nullptr, 1024, 160, GY, rowOff, flag);
    // dec2: recon = sigmoid(hd @ W4 + b4), N=768 K=1024 (f32 scatter)
    gemm_k<2><<<dim3(12 * GY), dim3(256), 0, stream>>>(hc, DW2t, db2, nullptr, out, nullptr, 768, 1024, GY, rowOff, flag);
  }
}

// Round 7
// 284.830 us; speedup vs baseline: 1.1233x; 1.1233x over previous
//
#include <hip/hip_runtime.h>

typedef unsigned short u16;
typedef unsigned int   u32;
typedef __bf16 bf16x8 __attribute__((ext_vector_type(8)));
typedef float  f32x4  __attribute__((ext_vector_type(4)));

__device__ __forceinline__ u16 f2b(float f) {
  u32 u = __builtin_bit_cast(u32, f);
  u = (u + 0x7fffu + ((u >> 16) & 1u)) >> 16;   // RNE
  return (u16)u;
}
__device__ __forceinline__ float b2f(u16 h) {
  u32 u = ((u32)h) << 16;
  return __builtin_bit_cast(float, u);
}
__device__ __forceinline__ float ld_in(const void* p, size_t idx, int isf32) {
  return isf32 ? ((const float*)p)[idx] : b2f(((const u16*)p)[idx]);
}
// async 16B global->LDS; HW semantics: LDS dest = wave-uniform base + lane*16
__device__ __forceinline__ void async_cp16(const u16* g, u16* l) {
  __builtin_amdgcn_global_load_lds(
      (const __attribute__((address_space(1))) void*)g,
      (__attribute__((address_space(3))) void*)l, 16, 0, 0);
}

// Constants: BS=1024, CH=3, IMG=64, K=16, NC=10, HID=1024, LAT=128
// OH=4, L=16, PD=768, M=16384. ws observed 256MB -> single pass R=16384.
#define RECON_ELEMS 12582912   // 1024*3*64*64

// ---------------------------------------------------------------------------
// dtype detector: bf16 uniform[0,1) values are u16 in [0,0x3F80], sign=0.
// ---------------------------------------------------------------------------
__global__ __launch_bounds__(256) void detect_f32(const u16* __restrict__ x,
                                                  int* __restrict__ flag) {
  __shared__ int s;
  if (threadIdx.x == 0) s = 0;
  __syncthreads();
  int bad = 0;
  for (int i = threadIdx.x; i < 2048; i += 256) {
    u16 u = x[i];
    if ((u & 0x8000u) || (u > 0x3F80u)) bad = 1;
  }
  if (bad) atomicOr(&s, 1);
  __syncthreads();
  if (threadIdx.x == 0) *flag = s;
}

// ---------------------------------------------------------------------------
// A1 chunk (R x 800 bf16): [patch(768) | c(10) | zeros(22)]
// ---------------------------------------------------------------------------
__global__ __launch_bounds__(256) void build_a1(const void* __restrict__ x,
                                                const void* __restrict__ c,
                                                u16* __restrict__ A1,
                                                int R, int rowOff,
                                                const int* __restrict__ flag) {
  int g = blockIdx.x * 256 + threadIdx.x;          // R * 100 groups of 8 cols
  if (g >= R * 100) return;
  int row = g / 100, grp = g - row * 100;
  int grow = row + rowOff;
  int b = grow >> 4, l = grow & 15, oh = l >> 2, ow = l & 3;
  int isf = *flag;
  u16* dst = &A1[(size_t)row * 800 + grp * 8];
  int col0 = grp * 8;
  if (col0 < 768) {
    int ch = col0 >> 8, kh = (col0 >> 4) & 15, kw = col0 & 15;  // kw in {0,8}
    size_t off = (size_t)b * 12288 + ch * 4096 + (oh * 16 + kh) * 64 + ow * 16 + kw;
    if (isf) {
      const float* s = (const float*)x + off;
      float4 f0 = *(const float4*)(s);
      float4 f1 = *(const float4*)(s + 4);
      dst[0] = f2b(f0.x); dst[1] = f2b(f0.y); dst[2] = f2b(f0.z); dst[3] = f2b(f0.w);
      dst[4] = f2b(f1.x); dst[5] = f2b(f1.y); dst[6] = f2b(f1.z); dst[7] = f2b(f1.w);
    } else {
      *(int4*)dst = *(const int4*)((const u16*)x + off);
    }
  } else {
#pragma unroll
    for (int t = 0; t < 8; ++t) {
      int col = col0 + t;
      dst[t] = (col < 778) ? f2b(ld_in(c, (size_t)b * 10 + (col - 768), isf)) : (u16)0;
    }
  }
}

// ---------------------------------------------------------------------------
// Fused weight prep: 4 transposes in one dispatch (blockIdx.z selects).
// dst (N x Kpad) = src(Ksrc x N)^T, zero-pad k>=Ksrc. 32x32 LDS tile.
// ---------------------------------------------------------------------------
__global__ __launch_bounds__(256) void prep_weights(const void* __restrict__ ew1,
                                                    const void* __restrict__ ew2,
                                                    const void* __restrict__ dw1,
                                                    const void* __restrict__ dw2,
                                                    u16* __restrict__ W1t,
                                                    u16* __restrict__ EW2t,
                                                    u16* __restrict__ W3t,
                                                    u16* __restrict__ DW2t,
                                                    const int* __restrict__ flag) {
  const int z = blockIdx.z;
  const void* src; u16* dst; int N, Kpad, Ksrc;
  if (z == 0)      { src = ew1; dst = W1t;  N = 1024; Kpad = 800;  Ksrc = 778;  }
  else if (z == 1) { src = ew2; dst = EW2t; N = 256;  Kpad = 1024; Ksrc = 1024; }
  else if (z == 2) { src = dw1; dst = W3t;  N = 1024; Kpad = 160;  Ksrc = 138;  }
  else             { src = dw2; dst = DW2t; N = 768;  Kpad = 1024; Ksrc = 1024; }
  const int k0 = blockIdx.x * 32, n0 = blockIdx.y * 32;
  if (k0 >= Kpad || n0 >= N) return;
  __shared__ float t[32][33];
  const int tx = threadIdx.x & 31, ty = threadIdx.x >> 5;   // 32 x 8
  const int isf = *flag;
#pragma unroll
  for (int j = 0; j < 4; ++j) {
    int k = k0 + ty + j * 8;
    t[ty + j * 8][tx] = (k < Ksrc) ? ld_in(src, (size_t)k * N + n0 + tx, isf) : 0.0f;
  }
  __syncthreads();
#pragma unroll
  for (int j = 0; j < 4; ++j) {
    int n = n0 + ty + j * 8;
    dst[(size_t)n * Kpad + k0 + tx] = f2b(t[tx][ty + j * 8]);
  }
}

// A3 chunk tail cols 128..159: [c(10) | zeros(22)]
__global__ __launch_bounds__(256) void build_a3_tail(const void* __restrict__ c,
                                                     u16* __restrict__ A3,
                                                     int R, int rowOff,
                                                     const int* __restrict__ flag) {
  int i = blockIdx.x * 256 + threadIdx.x;          // R*32
  if (i >= R * 32) return;
  int row = i >> 5, col = 128 + (i & 31);
  int b = (row + rowOff) >> 4;
  int isf = *flag;
  A3[(size_t)row * 160 + col] = (col < 138) ? f2b(ld_in(c, (size_t)b * 10 + col - 128, isf)) : (u16)0;
}

// ---------------------------------------------------------------------------
// MFMA GEMM, software-pipelined: C(R x N) = act(A @ Bt^T + bias)
// 128x128 tile, BK=32, 4 waves (2x2), 4x4 16x16x32 MFMA per wave (16/iter).
// DOUBLE-BUFFERED LDS with raw s_barrier + fine s_waitcnt vmcnt(4): the next
// tile's 4 global_load_lds stay IN FLIGHT across the barrier and the whole
// MFMA phase (rounds 5/6 showed the vmcnt(0)-drain chain ~885cyc/iter is the
// limiter: occupancy 23->60% changed nothing). Bias/flag loads are drained
// by a vmcnt(0) fence BEFORE the prologue so the vmcnt ledger stays exact.
// 1D grid, by=bid%GY (GY%8==0 -> XCD=by%8): A-tile sharers colocate (round-5
// verified: FETCH ideal). LDS 16B XOR swizzle (round-5 verified: 0 conflicts).
// EPI: 0 = ReLU -> bf16 outb row-major (ld=N)
//      1 = none -> f32 outf = mu_logvar_2d scatter, bf16 out1 = A3 mu (ld=160)
//      2 = sigmoid -> f32 outf = recon scatter
// ---------------------------------------------------------------------------
template <int EPI>
__global__ __launch_bounds__(256, 3) void gemm_k(const u16* __restrict__ A,
                                                 const u16* __restrict__ Bt,
                                                 const void* __restrict__ bias,
                                                 u16* __restrict__ outb,
                                                 float* __restrict__ outf,
                                                 u16* __restrict__ out1,
                                                 int N, int K, int GY, int rowOff,
                                                 const int* __restrict__ flag) {
  __shared__ __align__(16) u16 As[2][128 * 32];
  __shared__ __align__(16) u16 Bs[2][128 * 32];
  const int bid = blockIdx.x;
  const int by = bid % GY, bx = bid / GY;
  const int rowBase = by * 128, colBase = bx * 128;
  const int tid  = threadIdx.x;
  const int lane = tid & 63;
  const int wave = tid >> 6;
  const int wr = (wave >> 1) * 64, wc = (wave & 1) * 64;
  const int quad = lane >> 4, l16 = lane & 15;
  const int swq = quad ^ ((l16 >> 1) & 3);          // XOR-swizzled quad slot

  // epilogue scalars FIRST, then drain, so loop vmcnt counts are exact
  const int isf = *flag;
  float bv[4];
#pragma unroll
  for (int j = 0; j < 4; ++j) bv[j] = ld_in(bias, colBase + wc + j * 16 + l16, isf);
  asm volatile("s_waitcnt vmcnt(0)" ::: "memory");

  // staging map: LDS slot s <- global chunk (r=s>>2, q=(s&3)^((s>>3)&3))
  const int s0 = tid, s1 = 256 + tid;
  const int r0 = s0 >> 2, q0 = (s0 & 3) ^ ((s0 >> 3) & 3);
  const int r1 = s1 >> 2, q1 = (s1 & 3) ^ ((s1 >> 3) & 3);
  const u16* gA0 = &A[(size_t)(rowBase + r0) * K + q0 * 8];
  const u16* gA1 = &A[(size_t)(rowBase + r1) * K + q1 * 8];
  const u16* gB0 = &Bt[(size_t)(colBase + r0) * K + q0 * 8];
  const u16* gB1 = &Bt[(size_t)(colBase + r1) * K + q1 * 8];

  f32x4 acc[4][4] = {};
  const int NI = K >> 5;

  // prologue: stage tile 0 into buffer 0  (4 loads in flight)
  async_cp16(gA0, &As[0][s0 * 8]);
  async_cp16(gA1, &As[0][s1 * 8]);
  async_cp16(gB0, &Bs[0][s0 * 8]);
  async_cp16(gB1, &Bs[0][s1 * 8]);

  int p = 0;
  for (int it = 0; it < NI; ++it) {
    if (it + 1 < NI) {
      const int kn = (it + 1) << 5;
      const int np = p ^ 1;
      async_cp16(gA0 + kn, &As[np][s0 * 8]);
      async_cp16(gA1 + kn, &As[np][s1 * 8]);
      async_cp16(gB0 + kn, &Bs[np][s0 * 8]);
      async_cp16(gB1 + kn, &Bs[np][s1 * 8]);
      // wait only the 4 OLD loads (buf p ready); 4 new stay in flight
      asm volatile("s_waitcnt vmcnt(4)\n\ts_barrier" ::: "memory");
    } else {
      asm volatile("s_waitcnt vmcnt(0)\n\ts_barrier" ::: "memory");
    }
    const u16* Ap = As[p];
    const u16* Bp = Bs[p];
    bf16x8 af[4], bfr[4];
#pragma unroll
    for (int i = 0; i < 4; ++i)
      af[i] = *(const bf16x8*)(&Ap[(wr + i * 16 + l16) * 32 + swq * 8]);
#pragma unroll
    for (int j = 0; j < 4; ++j)
      bfr[j] = *(const bf16x8*)(&Bp[(wc + j * 16 + l16) * 32 + swq * 8]);
#pragma unroll
    for (int i = 0; i < 4; ++i)
#pragma unroll
      for (int j = 0; j < 4; ++j)
        acc[i][j] = __builtin_amdgcn_mfma_f32_16x16x32_bf16(af[i], bfr[j], acc[i][j], 0, 0, 0);
    // reads of buf p retired before anyone re-stages into it next iter
    asm volatile("s_waitcnt lgkmcnt(0)\n\ts_barrier" ::: "memory");
    p ^= 1;
  }

#pragma unroll
  for (int i = 0; i < 4; ++i) {
    int row0 = rowBase + wr + i * 16 + quad * 4;   // chunk-local
#pragma unroll
    for (int j = 0; j < 4; ++j) {
      int col = colBase + wc + j * 16 + l16;
#pragma unroll
      for (int r = 0; r < 4; ++r) {
        int row = row0 + r;                        // chunk-local
        int grow = row + rowOff;                   // global
        float v = acc[i][j][r] + bv[j];
        if (EPI == 0) {
          v = fmaxf(v, 0.0f);
          outb[(size_t)row * N + col] = f2b(v);
        } else if (EPI == 1) {
          int b = grow >> 4, lr = grow & 15;
          outf[(size_t)b * 4096 + col * 16 + lr] = v;            // mu_logvar_2d (f32)
          if (col < 128) out1[(size_t)row * 160 + col] = f2b(v);  // A3 mu (bf16)
        } else {
          v = 1.0f / (1.0f + __expf(-v));
          int b = grow >> 4, l = grow & 15;
          int oh = l >> 2, ow = l & 3;
          int ch = col >> 8, kh = (col >> 4) & 15, kw = col & 15;
          outf[(size_t)b * 12288 + ch * 4096 + (oh * 16 + kh) * 64 + ow * 16 + kw] = v;
        }
      }
    }
  }
}

// ---------------------------------------------------------------------------
// Workspace (u16 element offsets):
//   flag @ 0 (8 u16 incl pad) | W1t 1024x800 | EW2t 256x1024 | W3t 1024x160
//   DW2t 768x1024 | A1c Rx800 | hc Rx1024 | A3c Rx160
// bytes = 2*(2031624 + R*1984); R=16384 -> 69.1 MB (ws observed = 256 MB)
// ---------------------------------------------------------------------------

extern "C" void kernel_launch(void* const* d_in, const int* in_sizes, int n_in,
                              void* d_out, int out_size, void* d_ws, size_t ws_size,
                              hipStream_t stream) {
  const void* x   = d_in[0];
  const void* c   = d_in[1];
  const void* ew1 = d_in[2];
  const void* eb1 = d_in[3];
  const void* ew2 = d_in[4];
  const void* eb2 = d_in[5];
  const void* dw1 = d_in[6];
  const void* db1 = d_in[7];
  const void* dw2 = d_in[8];
  const void* db2 = d_in[9];
  float* out  = (float*)d_out;
  u16*   ws   = (u16*)d_ws;

  const size_t fixedU16 = 8 + 819200 + 262144 + 163840 + 786432;  // 2,031,624
  int R = 128;
  for (int cand = 16384; cand >= 128; cand >>= 1) {
    if ((fixedU16 + (size_t)cand * 1984) * 2 <= ws_size) { R = cand; break; }
  }

  int* flag = (int*)ws;
  u16* W1t  = ws + 8;
  u16* EW2t = W1t + 819200;
  u16* W3t  = EW2t + 262144;
  u16* DW2t = W3t + 163840;
  u16* A1c  = DW2t + 786432;
  u16* hc   = A1c + (size_t)R * 800;
  u16* A3c  = hc + (size_t)R * 1024;
  float* out2 = out + RECON_ELEMS;

  detect_f32<<<dim3(1), dim3(256), 0, stream>>>((const u16*)x, flag);

  prep_weights<<<dim3(32, 32, 4), dim3(256), 0, stream>>>(ew1, ew2, dw1, dw2,
                                                          W1t, EW2t, W3t, DW2t, flag);

  const int chunks = 16384 / R;
  const int GY = R / 128;
  for (int chunk = 0; chunk < chunks; ++chunk) {
    int rowOff = chunk * R;
    build_a1<<<dim3((R * 100 + 255) / 256), dim3(256), 0, stream>>>(x, c, A1c, R, rowOff, flag);
    build_a3_tail<<<dim3((R * 32) / 256), dim3(256), 0, stream>>>(c, A3c, R, rowOff, flag);
    // enc1: h = relu(A1 @ W1 + b1), N=1024 K=800
    gemm_k<0><<<dim3(8 * GY), dim3(256), 0, stream>>>(A1c, W1t, eb1, hc, nullptr, nullptr, 1024, 800, GY, rowOff, flag);
    // enc2: mu_logvar = h @ W2 + b2, N=256 K=1024 (f32 scatter + A3 mu)
    gemm_k<1><<<dim3(2 * GY), dim3(256), 0, stream>>>(hc, EW2t, eb2, nullptr, out2, A3c, 256, 1024, GY, rowOff, flag);
    // dec1: hd = relu(A3 @ W3 + b3), N=1024 K=160
    gemm_k<0><<<dim3(8 * GY), dim3(256), 0, stream>>>(A3c, W3t, db1, hc, nullptr, nullptr, 1024, 160, GY, rowOff, flag);
    // dec2: recon = sigmoid(hd @ W4 + b4), N=768 K=1024 (f32 scatter)
    gemm_k<2><<<dim3(12 * GY / 2), dim3(256), 0, stream>>>(hc, DW2t, db2, nullptr, out, nullptr, 768, 1024, GY, rowOff, flag);
  }
}